// Round 8
// baseline (73.406 us; speedup 1.0000x reference)
//
#include <hip/hip_runtime.h>
#include <hip/hip_bf16.h>

#define B_SZ   2048
#define F_IN   1024
#define R_EMB  1024
#define F_OUT  1024
#define F_MID  2048
#define NNZ_E  65536
#define NNZ_W  131072
#define NNZ_B  512

typedef __bf16 bf16x8 __attribute__((ext_vector_type(8)));
typedef float  f32x4  __attribute__((ext_vector_type(4)));

__device__ inline void gload16(const void* g, void* l) {
    __builtin_amdgcn_global_load_lds(
        (const __attribute__((address_space(1))) void*)g,
        (__attribute__((address_space(3))) void*)l, 16, 0, 0);
}

__device__ inline ushort f2bf(float v) {
    __hip_bfloat16 h = __float2bfloat16(v);
    return *reinterpret_cast<ushort*>(&h);
}

__global__ void k_zero4(float4* __restrict__ p, int n) {
    int i = blockIdx.x * blockDim.x + threadIdx.x;
    if (i < n) p[i] = make_float4(0.f, 0.f, 0.f, 0.f);
}

// One launch for all three scatter-adds (blocks partitioned by range).
__global__ void k_scatter_fused(const int* __restrict__ er, const int* __restrict__ ec,
                                const float* __restrict__ ev,
                                const int* __restrict__ wr_, const int* __restrict__ wc_,
                                const float* __restrict__ wv,
                                const int* __restrict__ bi, const float* __restrict__ bv,
                                float* __restrict__ Ef, float* __restrict__ Wf,
                                float* __restrict__ biasd) {
    int b = blockIdx.x, t = threadIdx.x;
    if (b < NNZ_E / 256) {
        int i = b * 256 + t;
        atomicAdd(&Ef[(size_t)er[i] * F_IN + ec[i]], ev[i]);
    } else if (b < NNZ_E / 256 + NNZ_W / 256) {
        int i = (b - NNZ_E / 256) * 256 + t;
        atomicAdd(&Wf[(size_t)wr_[i] * F_MID + wc_[i]], wv[i]);
    } else {
        int i = t;
        atomicAdd(&biasd[bi[i]], bv[i]);
        i += 256;
        atomicAdd(&biasd[bi[i]], bv[i]);
    }
}

// One launch for all three f32->bf16 conversions.
__global__ void k_cvt_fused(const float4* __restrict__ x, ushort* __restrict__ x2,
                            const float4* __restrict__ Ef, ushort* __restrict__ Ebf,
                            const float4* __restrict__ Wf, ushort* __restrict__ Wbf) {
    int b = blockIdx.x, t = threadIdx.x;
    if (b < 2048) {
        int i = b * 256 + t;                 // float4 index into x
        int row = i >> 8, c4 = i & 255;      // 256 float4 per row of 1024
        float4 v = x[i];
        ((ushort4*)x2)[(size_t)row * (F_MID / 4) + c4] =
            make_ushort4(f2bf(v.x), f2bf(v.y), f2bf(v.z), f2bf(v.w));
    } else if (b < 3072) {
        int i = (b - 2048) * 256 + t;
        float4 v = Ef[i];
        ((ushort4*)Ebf)[i] = make_ushort4(f2bf(v.x), f2bf(v.y), f2bf(v.z), f2bf(v.w));
    } else {
        int i = (b - 3072) * 256 + t;
        float4 v = Wf[i];
        ((ushort4*)Wbf)[i] = make_ushort4(f2bf(v.x), f2bf(v.y), f2bf(v.z), f2bf(v.w));
    }
}

// 128x128 block tile, BK=64, 4 waves (2x2) of 64x64 wave tiles, 16x16x32 MFMA.
// FLOP/ds_read_b128 = 32768 (2x round-6 structure) -> LDS-BW ceiling ~1678 TF.
// Counted-vmcnt 2-buffer pipeline: stage t+1's 8 global_load_lds stay in flight
// across compute(t); s_waitcnt vmcnt(8) waits only for stage t.  Full 8-slot
// XOR swizzle (row stride 128 B): LDS slot s of row r holds global chunk
// s ^ (r&7); reads XOR the same way (both-sides involution, linear LDS dest).
//   PHASE 0, by < 8 : mode 0  h = relu(x @ E^T)       (bf16 -> x2 right half)
//   PHASE 0, by >= 8: mode 1  out = x @ W_L^T + bias  (f32)
//   PHASE 1         : mode 2  out += h @ W_R^T        (split-K=2, f32 atomics)
template <int PHASE>
__global__ __launch_bounds__(256)
void k_gemm128(const ushort* __restrict__ x2,   // [2048][2048] bf16
               const ushort* __restrict__ Ebf,  // [1024][1024] bf16
               const ushort* __restrict__ Wbf,  // [1024][2048] bf16
               const float* __restrict__ biasd, // [1024]
               float* __restrict__ out,         // [2048][1024] f32
               ushort* __restrict__ hOut)       // = x2 + F_IN
{
    constexpr int BK = 64;
    constexpr int NT = (PHASE == 0) ? 16 : 8;    // K-tiles (phase 1: K=512 per split)
    __shared__ ushort lA[2][128 * BK];           // 2 x 16 KB
    __shared__ ushort lB[2][128 * BK];           // 2 x 16 KB
    const int tid = threadIdx.x;
    const int w = tid >> 6, l = tid & 63;
    const int wr = w >> 1, wc = w & 1;
    const int la = l & 15, lg = l >> 4;          // fragment row / k-group
    const int m0 = blockIdx.x * 128;
    const int by = blockIdx.y;

    int mode, n0, kbase = 0, ldb;
    const ushort* Bm;
    const ushort* A;
    if (PHASE == 0) {
        if (by < 8) { mode = 0; A = x2;        Bm = Ebf;        ldb = F_IN;  n0 = by * 128; }
        else        { mode = 1; A = x2;        Bm = Wbf;        ldb = F_MID; n0 = (by - 8) * 128; }
    } else {
        mode = 2;     A = x2 + F_IN; Bm = Wbf + F_IN; ldb = F_MID;
        n0 = (by & 7) * 128; kbase = (by >> 3) * 512;
    }

    // Staging: pass i covers 32 rows; thread t -> row i*32+(t>>3), slot t&7.
    const int srow = tid >> 3, sslot = tid & 7;

    f32x4 acc[4][4] = {};

    #define STAGE(buf, k0)                                                      \
        _Pragma("unroll")                                                       \
        for (int i = 0; i < 4; ++i) {                                           \
            int row = i * 32 + srow;                                            \
            int col = (k0) + ((sslot ^ (row & 7)) << 3);                        \
            gload16(A + (size_t)(m0 + row) * F_MID + col,                       \
                    &lA[buf][i * 2048 + tid * 8]);                              \
        }                                                                       \
        _Pragma("unroll")                                                       \
        for (int i = 0; i < 4; ++i) {                                           \
            int row = i * 32 + srow;                                            \
            int col = (k0) + ((sslot ^ (row & 7)) << 3);                        \
            gload16(Bm + (size_t)(n0 + row) * ldb + col,                        \
                    &lB[buf][i * 2048 + tid * 8]);                              \
        }

    auto compute = [&](int cur) {
        const ushort* sA = &lA[cur][0];
        const ushort* sB = &lB[cur][0];
        #pragma unroll
        for (int ks = 0; ks < 2; ++ks) {
            const int c = ks * 4 + lg;              // 8-elem chunk 0..7
            bf16x8 af[4], bg[4];
            #pragma unroll
            for (int m = 0; m < 4; ++m) {
                int row = wr * 64 + m * 16 + la;    // row&7 == la&7
                af[m] = *(const bf16x8*)(sA + row * BK + ((c ^ (row & 7)) << 3));
            }
            #pragma unroll
            for (int n = 0; n < 4; ++n) {
                int row = wc * 64 + n * 16 + la;
                bg[n] = *(const bf16x8*)(sB + row * BK + ((c ^ (row & 7)) << 3));
            }
            #pragma unroll
            for (int m = 0; m < 4; ++m)
                #pragma unroll
                for (int n = 0; n < 4; ++n)
                    acc[m][n] = __builtin_amdgcn_mfma_f32_16x16x32_bf16(
                        af[m], bg[n], acc[m][n], 0, 0, 0);
        }
    };

    STAGE(0, kbase);                              // stage 0: 8 loads in flight

    for (int t = 0; t < NT - 1; ++t) {
        STAGE((t + 1) & 1, kbase + (t + 1) * BK); // stage t+1: 8 more loads
        asm volatile("s_waitcnt vmcnt(8)" ::: "memory");   // stage t complete
        __builtin_amdgcn_s_barrier();
        __builtin_amdgcn_sched_barrier(0);
        compute(t & 1);
        __builtin_amdgcn_sched_barrier(0);
        __builtin_amdgcn_s_barrier();             // seal reads before overwrite
    }
    asm volatile("s_waitcnt vmcnt(0)" ::: "memory");
    __builtin_amdgcn_s_barrier();
    __builtin_amdgcn_sched_barrier(0);
    compute((NT - 1) & 1);
    #undef STAGE

    // C/D layout (verified m89/m91): col = lane&15, row = (lane>>4)*4 + reg.
    const int lr = lg * 4;
    #pragma unroll
    for (int m = 0; m < 4; ++m) {
        #pragma unroll
        for (int n = 0; n < 4; ++n) {
            const int col = n0 + wc * 64 + n * 16 + la;
            if (mode == 0) {
                #pragma unroll
                for (int j = 0; j < 4; ++j) {
                    int row = m0 + wr * 64 + m * 16 + lr + j;
                    hOut[(size_t)row * F_MID + col] = f2bf(fmaxf(acc[m][n][j], 0.f));
                }
            } else if (mode == 1) {
                const float bv = biasd[col];
                #pragma unroll
                for (int j = 0; j < 4; ++j) {
                    int row = m0 + wr * 64 + m * 16 + lr + j;
                    out[(size_t)row * F_OUT + col] = acc[m][n][j] + bv;
                }
            } else {
                #pragma unroll
                for (int j = 0; j < 4; ++j) {
                    int row = m0 + wr * 64 + m * 16 + lr + j;
                    unsafeAtomicAdd(&out[(size_t)row * F_OUT + col], acc[m][n][j]);
                }
            }
        }
    }
}

extern "C" void kernel_launch(void* const* d_in, const int* in_sizes, int n_in,
                              void* d_out, int out_size, void* d_ws, size_t ws_size,
                              hipStream_t stream) {
    const float* x          = (const float*)d_in[0];
    const int*   embed_rows = (const int*)  d_in[1];
    const int*   embed_cols = (const int*)  d_in[2];
    const float* embed_vals = (const float*)d_in[3];
    const int*   w_rows     = (const int*)  d_in[4];
    const int*   w_cols     = (const int*)  d_in[5];
    const float* w_vals     = (const float*)d_in[6];
    const int*   bias_idx   = (const int*)  d_in[7];
    const float* bias_vals  = (const float*)d_in[8];
    float* out = (float*)d_out;

    // Workspace layout (~26 MB):
    //   [0, 8M)          x2 bf16 [2048][2048]  (left = x, right = relu h)
    //   [8M, 16M)        W_f32 [1024][2048]
    //   [16M, 20M)       E_f32 [1024][1024]
    //   [20M, 20M+4K)    bias f32 [1024]
    //   [20M+4K, 22M+4K) E_bf16 [1024][1024]
    //   [22M+4K, 26M+4K) W_bf16 [1024][2048]
    char* ws = (char*)d_ws;
    ushort* x2    = (ushort*)ws;
    float*  Wf    = (float*)(ws + (8u << 20));
    float*  Ef    = (float*)(ws + (16u << 20));
    float*  biasd = (float*)(ws + (20u << 20));
    ushort* Ebf   = (ushort*)(ws + (20u << 20) + 4096);
    ushort* Wbf   = (ushort*)(ws + (22u << 20) + 4096);

    // 1. zero Wf | Ef | bias (12 MB + 4 KB = 786688 float4).  Own kernel, not
    //    hipMemsetAsync (runtime fill for this size measured ~285 GB/s, round 4).
    k_zero4<<<3073, 256, 0, stream>>>((float4*)(ws + (8u << 20)), 786688);

    // 2. densify all sparse inputs (one launch)
    k_scatter_fused<<<NNZ_E / 256 + NNZ_W / 256 + 1, 256, 0, stream>>>(
        embed_rows, embed_cols, embed_vals,
        w_rows, w_cols, w_vals,
        bias_idx, bias_vals, Ef, Wf, biasd);

    // 3. all f32 -> bf16 conversions (one launch)
    k_cvt_fused<<<5120, 256, 0, stream>>>((const float4*)x, x2,
                                          (const float4*)Ef, Ebf,
                                          (const float4*)Wf, Wbf);

    // 4. Phase A: {h = relu(x @ E^T)} || {out = x @ W_L^T + bias}, 256 blocks.
    k_gemm128<0><<<dim3(B_SZ / 128, 16), 256, 0, stream>>>(
        x2, Ebf, Wbf, biasd, out, x2 + F_IN);

    // 5. Phase B: out += h @ W_R^T, split-K=2, 256 blocks, f32 atomics.
    k_gemm128<1><<<dim3(B_SZ / 128, 16), 256, 0, stream>>>(
        x2, Ebf, Wbf, biasd, out, x2 + F_IN);
}